// Round 4
// baseline (1014.913 us; speedup 1.0000x reference)
//
#include <hip/hip_runtime.h>
#include <hip/hip_bf16.h>
#include <hip/hip_cooperative_groups.h>

namespace cg = cooperative_groups;

#define NNODES 50000
#define NEDGES 800000
#define IN_DIM 128
#define EDGE_DIM 32
#define OUT_DIM 128
#define KDIM 160          // IN_DIM + EDGE_DIM
#define A_STRIDE 168      // 160 + 8 pad: kills 8-way LDS bank conflict, 16B align
#define NS 136            // 128 + 8 pad for node phase
#define MS2 130           // bf16 m-tile stride
#define NT (NEDGES / 64)  // 12500 edge tiles
#define EG 512            // cooperative grid: exactly 2 blocks/CU
#define TPB ((NT + EG - 1) / EG)       // 25 tiles per block
#define NTN ((NNODES + 63) / 64)       // 782 node tiles
#define CHUNK 98                       // 512*98 = 50176 >= 50000

typedef __attribute__((ext_vector_type(8))) short short8;
typedef __attribute__((ext_vector_type(4))) short short4v;
typedef __attribute__((ext_vector_type(4))) float floatx4;

__device__ __forceinline__ short f2bf(float f) {
    union { float f; unsigned u; } v; v.f = f;
    unsigned r = (v.u + 0x7FFFu + ((v.u >> 16) & 1u)) >> 16;  // RNE
    return (short)r;
}

__device__ __forceinline__ void store_bf4(short* p, floatx4 v) {
    short4v s;
    s.x = f2bf(v.x); s.y = f2bf(v.y); s.z = f2bf(v.z); s.w = f2bf(v.w);
    *(short4v*)p = s;
}

#define MFMA8(ACC, A0, A1, B0, B1, B2, B3)                                        \
    ACC[0][0] = __builtin_amdgcn_mfma_f32_16x16x32_bf16(A0, B0, ACC[0][0], 0, 0, 0); \
    ACC[0][1] = __builtin_amdgcn_mfma_f32_16x16x32_bf16(A0, B1, ACC[0][1], 0, 0, 0); \
    ACC[0][2] = __builtin_amdgcn_mfma_f32_16x16x32_bf16(A0, B2, ACC[0][2], 0, 0, 0); \
    ACC[0][3] = __builtin_amdgcn_mfma_f32_16x16x32_bf16(A0, B3, ACC[0][3], 0, 0, 0); \
    ACC[1][0] = __builtin_amdgcn_mfma_f32_16x16x32_bf16(A1, B0, ACC[1][0], 0, 0, 0); \
    ACC[1][1] = __builtin_amdgcn_mfma_f32_16x16x32_bf16(A1, B1, ACC[1][1], 0, 0, 0); \
    ACC[1][2] = __builtin_amdgcn_mfma_f32_16x16x32_bf16(A1, B2, ACC[1][2], 0, 0, 0); \
    ACC[1][3] = __builtin_amdgcn_mfma_f32_16x16x32_bf16(A1, B3, ACC[1][3], 0, 0, 0);

// ===========================================================================
// MEGA cooperative kernel: zero+weights | hist | partials | offsets | scatter
// | persistent pipelined edge GEMM+segmax | node GEMM.  One dispatch.
// LDS: As 21504 | Bs 43008 | mbufh 16640 | dsts 512 = 81664 -> 2 blocks/CU.
// ===========================================================================
__global__ __launch_bounds__(256, 2) void mega(
    const float* __restrict__ nfeat, const float* __restrict__ etype,
    const int* __restrict__ src, const int* __restrict__ dst,
    const float* __restrict__ W_edge, const float* __restrict__ W_ne,
    const float* __restrict__ b_ne, const float* __restrict__ W_self,
    const float* __restrict__ b_self, const float* __restrict__ eps,
    int* __restrict__ cnt, int* __restrict__ cur, int* __restrict__ part,
    int* __restrict__ perm, short* __restrict__ WcatB,
    short* __restrict__ WselfB, float* __restrict__ out)
{
    cg::grid_group gridg = cg::this_grid();
    __shared__ __align__(16) char SM[81664];
    short* As = (short*)SM;                          // 21504 B
    short* Bs = (short*)(SM + 21504);                // 43008 B
    unsigned short* mbufh = (unsigned short*)(SM + 64512);  // 16640 B
    int* dsts = (int*)(SM + 81152);                  // 2*64*4 = 512 B

    const int tid = threadIdx.x;
    const int bid = blockIdx.x;
    const int gid = bid * 256 + tid;
    const int GS = EG * 256;                         // 131072

    // ---------------- P0: zero out & cnt, build weights --------------------
    for (int i = gid; i < NNODES * OUT_DIM / 4; i += GS)
        ((floatx4*)out)[i] = (floatx4){0.f, 0.f, 0.f, 0.f};
    for (int i = gid; i < NNODES; i += GS) cnt[i] = 0;
    {
        int idx = gid;
        if (idx < OUT_DIM * KDIM) {
            int n = idx / KDIM, k = idx - n * KDIM;
            float val;
            if (k < IN_DIM) {
                val = W_ne[n * 256 + k];
            } else {
                int j = k - IN_DIM;
                float s = 0.f;
                for (int kk = 0; kk < 128; ++kk)
                    s += W_ne[n * 256 + 128 + kk] * W_edge[kk * 32 + j];
                val = s;
            }
            WcatB[idx] = f2bf(val);
        } else if (idx < OUT_DIM * KDIM + OUT_DIM * IN_DIM) {
            int s = idx - OUT_DIM * KDIM;
            WselfB[s] = f2bf(W_self[s]);
        }
    }
    __threadfence();
    gridg.sync();

    // ---------------- P1: histogram of dst ---------------------------------
    for (int e = gid; e < NEDGES; e += GS)
        atomicAdd(&cnt[dst[e]], 1);
    __threadfence();
    gridg.sync();

    // ---------------- P2: per-block chunk partial sums ----------------------
    {
        int* sr = (int*)SM;
        int beg = bid * CHUNK;
        int v = 0;
        if (tid < CHUNK && beg + tid < NNODES) v = cnt[beg + tid];
        sr[tid] = v;
        __syncthreads();
        for (int s = 128; s > 0; s >>= 1) {
            if (tid < s) sr[tid] += sr[tid + s];
            __syncthreads();
        }
        if (tid == 0) part[bid] = sr[0];
    }
    __threadfence();
    gridg.sync();

    // ---------------- P3: exclusive offsets -> cursor -----------------------
    {
        int* sr = (int*)SM;                 // 256 ints
        int* sv = (int*)(SM + 1024);        // 128 ints
        int* sw = (int*)(SM + 1536);        // 128 ints
        int a = 0;
        if (tid < bid) a += part[tid];
        if (tid + 256 < bid) a += part[tid + 256];
        sr[tid] = a;
        __syncthreads();
        for (int s = 128; s > 0; s >>= 1) {
            if (tid < s) sr[tid] += sr[tid + s];
            __syncthreads();
        }
        int pre = sr[0];
        __syncthreads();
        int beg = bid * CHUNK;
        int len = NNODES - beg;
        if (len > CHUNK) len = CHUNK;
        if (len < 0) len = 0;
        int v = (tid < len) ? cnt[beg + tid] : 0;
        if (tid < 128) sv[tid] = v;
        __syncthreads();
        int* pin = sv; int* pout = sw;
        for (int off = 1; off < 128; off <<= 1) {
            if (tid < 128) pout[tid] = pin[tid] + (tid >= off ? pin[tid - off] : 0);
            __syncthreads();
            int* tp = pin; pin = pout; pout = tp;
        }
        if (tid < len) cur[beg + tid] = pre + pin[tid] - v;  // exclusive
    }
    __threadfence();
    gridg.sync();

    // ---------------- P4: scatter permutation -------------------------------
    for (int e = gid; e < NEDGES; e += GS) {
        int pos = atomicAdd(&cur[dst[e]], 1);
        perm[pos] = e;
    }
    __threadfence();
    gridg.sync();

    // ---------------- P5: persistent pipelined edge phase -------------------
    {
        // stage B once (covered by first in-loop barrier)
        int r = tid >> 1, h = tid & 1;
        const short8* g = (const short8*)(WcatB + r * KDIM + h * 80);
        short* l = Bs + r * A_STRIDE + h * 80;
        #pragma unroll
        for (int c = 0; c < 10; ++c)
            *(short8*)(l + 8 * c) = g[c];
    }
    const int lane = tid & 63;
    const int w = tid >> 6;
    const int et = w & 1;
    const int nh = w >> 1;
    const int li = lane & 15, q = lane >> 4;
    const short* Ab = As + (et * 32 + li) * A_STRIDE + q * 8;
    const short* Bb = Bs + (nh * 64 + li) * A_STRIDE + q * 8;

    {
        float bias[4];
        #pragma unroll
        for (int tb = 0; tb < 4; ++tb) bias[tb] = b_ne[nh * 64 + tb * 16 + li];

        const int t0 = bid * TPB;
        const int t1 = min(t0 + TPB, NT);
        const int g16 = tid & 15, eo = tid >> 4;
        const int ee = tid >> 2, ec = tid & 3;

        floatx4 pnf[4][2];   // prefetched nfeat fragments
        floatx4 pet[2];      // prefetched etype fragment
        int pdst = 0;

        auto PREFETCH = [&](int t) {
            int e0 = t * 64;
            if (tid < 64) pdst = dst[perm[e0 + tid]];
            {
                int pe = perm[e0 + ee];
                const floatx4* row = (const floatx4*)(etype + (size_t)pe * 32);
                pet[0] = row[2 * ec];
                pet[1] = row[2 * ec + 1];
            }
            #pragma unroll
            for (int p = 0; p < 4; ++p) {
                int e = eo + p * 16;
                int s = src[perm[e0 + e]];
                const floatx4* row = (const floatx4*)(nfeat + (size_t)s * 128);
                pnf[p][0] = row[g16];
                pnf[p][1] = row[g16 + 16];
            }
        };
        auto COMMIT = [&](int par) {
            if (tid < 64) dsts[par * 64 + tid] = pdst;
            store_bf4(As + ee * A_STRIDE + IN_DIM + 8 * ec, pet[0]);
            store_bf4(As + ee * A_STRIDE + IN_DIM + 8 * ec + 4, pet[1]);
            #pragma unroll
            for (int p = 0; p < 4; ++p) {
                int e = eo + p * 16;
                store_bf4(As + e * A_STRIDE + 4 * g16, pnf[p][0]);
                store_bf4(As + e * A_STRIDE + 64 + 4 * g16, pnf[p][1]);
            }
        };

        if (t0 < t1) PREFETCH(t0);
        for (int t = t0; t < t1; ++t) {
            const int par = t & 1;
            COMMIT(par);
            __syncthreads();                 // A ready; everyone's scan(t-1) done
            if (t + 1 < t1) PREFETCH(t + 1); // overlaps MFMA + epilogue

            floatx4 acc[2][4];
            #pragma unroll
            for (int i = 0; i < 2; ++i)
                #pragma unroll
                for (int j = 0; j < 4; ++j)
                    acc[i][j] = (floatx4){0.f, 0.f, 0.f, 0.f};

            #pragma unroll
            for (int kk = 0; kk < 5; ++kk) {
                short8 a0 = *(const short8*)(Ab + kk * 32);
                short8 a1 = *(const short8*)(Ab + 16 * A_STRIDE + kk * 32);
                short8 b0 = *(const short8*)(Bb + kk * 32);
                short8 b1 = *(const short8*)(Bb + 16 * A_STRIDE + kk * 32);
                short8 b2 = *(const short8*)(Bb + 32 * A_STRIDE + kk * 32);
                short8 b3 = *(const short8*)(Bb + 48 * A_STRIDE + kk * 32);
                MFMA8(acc, a0, a1, b0, b1, b2, b3)
            }

            // m tile (relu+bias) -> mbufh; C/D: row = q*4+reg, col = li
            #pragma unroll
            for (int ta = 0; ta < 2; ++ta) {
                #pragma unroll
                for (int r2 = 0; r2 < 4; ++r2) {
                    int el = et * 32 + ta * 16 + q * 4 + r2;
                    #pragma unroll
                    for (int tb = 0; tb < 4; ++tb) {
                        int o = nh * 64 + tb * 16 + li;
                        float v = acc[ta][tb][r2] + bias[tb];
                        v = v > 0.f ? v : 0.f;
                        mbufh[el * MS2 + o] = (unsigned short)f2bf(v);
                    }
                }
            }
            __syncthreads();                 // mbuf ready

            // per-column run-max over dst-sorted rows; 1 atomic per run
            {
                int c = tid & 127, h2 = tid >> 7;
                int r0 = h2 * 32;
                const int* dd = dsts + par * 64;
                int curd = dd[r0];
                unsigned best = mbufh[r0 * MS2 + c];
                #pragma unroll 4
                for (int r2 = 1; r2 < 32; ++r2) {
                    int d = dd[r0 + r2];
                    unsigned bits = mbufh[(r0 + r2) * MS2 + c];
                    if (d != curd) {
                        atomicMax((int*)out + (size_t)curd * 128 + c,
                                  (int)(best << 16));
                        curd = d; best = bits;
                    } else {
                        best = best > bits ? best : bits;
                    }
                }
                atomicMax((int*)out + (size_t)curd * 128 + c, (int)(best << 16));
            }
        }
    }
    __threadfence();
    gridg.sync();

    // ---------------- P6: node phase ---------------------------------------
    {
        short* nAs = (short*)SM;             // 64*136*2 = 17408
        short* nBs = (short*)(SM + 21504);   // 128*136*2 = 34816
        {
            int r = tid >> 1, h = tid & 1;
            const short8* g = (const short8*)(WselfB + r * 128 + h * 64);
            short* l = nBs + r * NS + h * 64;
            #pragma unroll
            for (int c = 0; c < 8; ++c)
                *(short8*)(l + 8 * c) = g[c];
        }
        const short* nAb = nAs + (et * 32 + li) * NS + q * 8;
        const short* nBb = nBs + (nh * 64 + li) * NS + q * 8;
        const float epsv = 1.0f + eps[0];
        float sbias[4];
        #pragma unroll
        for (int tb = 0; tb < 4; ++tb) sbias[tb] = b_self[nh * 64 + tb * 16 + li];

        for (int tn = bid; tn < NTN; tn += EG) {
            const int n0 = tn * 64;
            __syncthreads();                 // As safe to restage; Bs visible
            {
                int r = tid >> 2, fi = tid & 3;
                int n = n0 + r;
                if (n < NNODES) {
                    const floatx4* row = (const floatx4*)(nfeat + (size_t)n * 128);
                    #pragma unroll
                    for (int p = 0; p < 8; ++p) {
                        int f = fi + 4 * p;
                        store_bf4(nAs + r * NS + 4 * f, row[f]);
                    }
                } else {
                    #pragma unroll
                    for (int p = 0; p < 8; ++p) {
                        int f = fi + 4 * p;
                        *(short4v*)(nAs + r * NS + 4 * f) = (short4v){0, 0, 0, 0};
                    }
                }
            }
            __syncthreads();

            floatx4 acc[2][4];
            #pragma unroll
            for (int i = 0; i < 2; ++i)
                #pragma unroll
                for (int j = 0; j < 4; ++j)
                    acc[i][j] = (floatx4){0.f, 0.f, 0.f, 0.f};

            #pragma unroll
            for (int kk = 0; kk < 4; ++kk) {
                short8 a0 = *(const short8*)(nAb + kk * 32);
                short8 a1 = *(const short8*)(nAb + 16 * NS + kk * 32);
                short8 b0 = *(const short8*)(nBb + kk * 32);
                short8 b1 = *(const short8*)(nBb + 16 * NS + kk * 32);
                short8 b2 = *(const short8*)(nBb + 32 * NS + kk * 32);
                short8 b3 = *(const short8*)(nBb + 48 * NS + kk * 32);
                MFMA8(acc, a0, a1, b0, b1, b2, b3)
            }

            #pragma unroll
            for (int ta = 0; ta < 2; ++ta) {
                #pragma unroll
                for (int r2 = 0; r2 < 4; ++r2) {
                    int n = n0 + et * 32 + ta * 16 + q * 4 + r2;
                    if (n < NNODES) {
                        #pragma unroll
                        for (int tb = 0; tb < 4; ++tb) {
                            int o = nh * 64 + tb * 16 + li;
                            float v = acc[ta][tb][r2] + sbias[tb]
                                    + epsv * out[(size_t)n * 128 + o];
                            out[(size_t)n * 128 + o] = v;
                        }
                    }
                }
            }
        }
    }
}

// ===========================================================================
// Fallback path (R3 multi-kernel) — used only if cooperative launch fails.
// ===========================================================================
__global__ void prep_weights(const float* __restrict__ W_edge,
                             const float* __restrict__ W_ne,
                             const float* __restrict__ W_self,
                             short* __restrict__ WcatB,
                             short* __restrict__ WselfB)
{
    int idx = blockIdx.x * 256 + threadIdx.x;
    if (idx < OUT_DIM * KDIM) {
        int n = idx / KDIM, k = idx - n * KDIM;
        float val;
        if (k < IN_DIM) {
            val = W_ne[n * 256 + k];
        } else {
            int j = k - IN_DIM;
            float s = 0.f;
            for (int kk = 0; kk < 128; ++kk)
                s += W_ne[n * 256 + 128 + kk] * W_edge[kk * 32 + j];
            val = s;
        }
        WcatB[idx] = f2bf(val);
    } else if (idx < OUT_DIM * KDIM + OUT_DIM * IN_DIM) {
        int s = idx - OUT_DIM * KDIM;
        WselfB[s] = f2bf(W_self[s]);
    }
}

__global__ void hist_kernel(const int* __restrict__ dst, int* __restrict__ cnt) {
    int e = blockIdx.x * 256 + threadIdx.x;
    if (e < NEDGES) atomicAdd(&cnt[dst[e]], 1);
}

__global__ __launch_bounds__(1024) void scan_kernel(const int* __restrict__ cnt,
                                                    int* __restrict__ off2) {
    __shared__ int bufA[1024], bufB[1024];
    const int CH = 49;
    int t = threadIdx.x;
    int beg = t * CH, end = min(beg + CH, NNODES);
    int s = 0;
    for (int i = beg; i < end; ++i) s += cnt[i];
    bufA[t] = s;
    __syncthreads();
    int* in = bufA; int* out = bufB;
    for (int off = 1; off < 1024; off <<= 1) {
        out[t] = in[t] + (t >= off ? in[t - off] : 0);
        __syncthreads();
        int* tmp = in; in = out; out = tmp;
    }
    int base = in[t] - s;
    for (int i = beg; i < end; ++i) { off2[i] = base; base += cnt[i]; }
}

__global__ void scatter_kernel(const int* __restrict__ dst,
                               int* __restrict__ off2,
                               int* __restrict__ perm) {
    int e = blockIdx.x * 256 + threadIdx.x;
    if (e < NEDGES) {
        int pos = atomicAdd(&off2[dst[e]], 1);
        perm[pos] = e;
    }
}

__global__ __launch_bounds__(256) void edge_kernel(
    const float* __restrict__ nfeat, const float* __restrict__ etype,
    const int* __restrict__ perm, const int* __restrict__ src,
    const int* __restrict__ dst, const float* __restrict__ b_ne,
    const short* __restrict__ WcatB, float* __restrict__ outmax)
{
    __shared__ short As[64 * A_STRIDE];
    __shared__ short Bs[128 * A_STRIDE];
    __shared__ unsigned short mbufh[64 * MS2];
    __shared__ int dsts[2][64];
    const int tid = threadIdx.x;
    {
        int r = tid >> 1, h = tid & 1;
        const short8* g = (const short8*)(WcatB + r * KDIM + h * 80);
        short* l = Bs + r * A_STRIDE + h * 80;
        #pragma unroll
        for (int c = 0; c < 10; ++c)
            *(short8*)(l + 8 * c) = g[c];
    }
    const int lane = tid & 63;
    const int w = tid >> 6;
    const int et = w & 1;
    const int nh = w >> 1;
    const int li = lane & 15, q = lane >> 4;
    const short* Ab = As + (et * 32 + li) * A_STRIDE + q * 8;
    const short* Bb = Bs + (nh * 64 + li) * A_STRIDE + q * 8;
    float bias[4];
    #pragma unroll
    for (int tb = 0; tb < 4; ++tb) bias[tb] = b_ne[nh * 64 + tb * 16 + li];
    const int t0 = blockIdx.x * TPB;
    const int t1 = min(t0 + TPB, NT);
    for (int t = t0; t < t1; ++t) {
        const int e0 = t * 64;
        const int par = t & 1;
        if (tid < 64) dsts[par][tid] = dst[perm[e0 + tid]];
        {
            int e = tid >> 2, c = tid & 3;
            int pe = perm[e0 + e];
            const floatx4* row = (const floatx4*)(etype + (size_t)pe * 32);
            floatx4 v0 = row[2 * c];
            floatx4 v1 = row[2 * c + 1];
            store_bf4(As + e * A_STRIDE + IN_DIM + 8 * c, v0);
            store_bf4(As + e * A_STRIDE + IN_DIM + 8 * c + 4, v1);
        }
        {
            int g = tid & 15, eo = tid >> 4;
            #pragma unroll
            for (int p = 0; p < 4; ++p) {
                int e = eo + p * 16;
                int s = src[perm[e0 + e]];
                const floatx4* row = (const floatx4*)(nfeat + (size_t)s * 128);
                floatx4 v0 = row[g];
                floatx4 v1 = row[g + 16];
                store_bf4(As + e * A_STRIDE + 4 * g, v0);
                store_bf4(As + e * A_STRIDE + 64 + 4 * g, v1);
            }
        }
        __syncthreads();
        floatx4 acc[2][4];
        #pragma unroll
        for (int i = 0; i < 2; ++i)
            #pragma unroll
            for (int j = 0; j < 4; ++j)
                acc[i][j] = (floatx4){0.f, 0.f, 0.f, 0.f};
        #pragma unroll
        for (int kk = 0; kk < 5; ++kk) {
            short8 a0 = *(const short8*)(Ab + kk * 32);
            short8 a1 = *(const short8*)(Ab + 16 * A_STRIDE + kk * 32);
            short8 b0 = *(const short8*)(Bb + kk * 32);
            short8 b1 = *(const short8*)(Bb + 16 * A_STRIDE + kk * 32);
            short8 b2 = *(const short8*)(Bb + 32 * A_STRIDE + kk * 32);
            short8 b3 = *(const short8*)(Bb + 48 * A_STRIDE + kk * 32);
            MFMA8(acc, a0, a1, b0, b1, b2, b3)
        }
        #pragma unroll
        for (int ta = 0; ta < 2; ++ta) {
            #pragma unroll
            for (int r = 0; r < 4; ++r) {
                int el = et * 32 + ta * 16 + q * 4 + r;
                #pragma unroll
                for (int tb = 0; tb < 4; ++tb) {
                    int o = nh * 64 + tb * 16 + li;
                    float v = acc[ta][tb][r] + bias[tb];
                    v = v > 0.f ? v : 0.f;
                    mbufh[el * MS2 + o] = (unsigned short)f2bf(v);
                }
            }
        }
        __syncthreads();
        {
            int c = tid & 127, h = tid >> 7;
            int r0 = h * 32;
            int curd = dsts[par][r0];
            unsigned best = mbufh[r0 * MS2 + c];
            #pragma unroll 4
            for (int r = 1; r < 32; ++r) {
                int d = dsts[par][r0 + r];
                unsigned bits = mbufh[(r0 + r) * MS2 + c];
                if (d != curd) {
                    atomicMax((int*)outmax + (size_t)curd * 128 + c,
                              (int)(best << 16));
                    curd = d; best = bits;
                } else {
                    best = best > bits ? best : bits;
                }
            }
            atomicMax((int*)outmax + (size_t)curd * 128 + c, (int)(best << 16));
        }
    }
}

__global__ __launch_bounds__(256) void node_kernel(
    const float* __restrict__ nfeat, const float* __restrict__ b_self,
    const float* __restrict__ eps, const short* __restrict__ WselfB,
    float* __restrict__ out)
{
    __shared__ short As[64 * NS];
    __shared__ short Bs[128 * NS];
    const int tid = threadIdx.x;
    const int n0 = blockIdx.x * 64;
    {
        int r = tid >> 1, h = tid & 1;
        const short8* g = (const short8*)(WselfB + r * 128 + h * 64);
        short* l = Bs + r * NS + h * 64;
        #pragma unroll
        for (int c = 0; c < 8; ++c)
            *(short8*)(l + 8 * c) = g[c];
    }
    {
        int r = tid >> 2, fi = tid & 3;
        int n = n0 + r;
        if (n < NNODES) {
            const floatx4* row = (const floatx4*)(nfeat + (size_t)n * 128);
            #pragma unroll
            for (int p = 0; p < 8; ++p) {
                int f = fi + 4 * p;
                store_bf4(As + r * NS + 4 * f, row[f]);
            }
        } else {
            #pragma unroll
            for (int p = 0; p < 8; ++p) {
                int f = fi + 4 * p;
                *(short4v*)(As + r * NS + 4 * f) = (short4v){0, 0, 0, 0};
            }
        }
    }
    __syncthreads();
    const int lane = tid & 63;
    const int w = tid >> 6;
    const int et = w & 1;
    const int nh = w >> 1;
    const int li = lane & 15, q = lane >> 4;
    floatx4 acc[2][4];
    #pragma unroll
    for (int i = 0; i < 2; ++i)
        #pragma unroll
        for (int j = 0; j < 4; ++j)
            acc[i][j] = (floatx4){0.f, 0.f, 0.f, 0.f};
    const short* Ab = As + (et * 32 + li) * NS + q * 8;
    const short* Bb = Bs + (nh * 64 + li) * NS + q * 8;
    #pragma unroll
    for (int kk = 0; kk < 4; ++kk) {
        short8 a0 = *(const short8*)(Ab + kk * 32);
        short8 a1 = *(const short8*)(Ab + 16 * NS + kk * 32);
        short8 b0 = *(const short8*)(Bb + kk * 32);
        short8 b1 = *(const short8*)(Bb + 16 * NS + kk * 32);
        short8 b2 = *(const short8*)(Bb + 32 * NS + kk * 32);
        short8 b3 = *(const short8*)(Bb + 48 * NS + kk * 32);
        MFMA8(acc, a0, a1, b0, b1, b2, b3)
    }
    const float epsv = 1.0f + eps[0];
    #pragma unroll
    for (int ta = 0; ta < 2; ++ta) {
        #pragma unroll
        for (int r = 0; r < 4; ++r) {
            int n = n0 + et * 32 + ta * 16 + q * 4 + r;
            if (n < NNODES) {
                #pragma unroll
                for (int tb = 0; tb < 4; ++tb) {
                    int o = nh * 64 + tb * 16 + li;
                    float v = acc[ta][tb][r] + b_self[o]
                            + epsv * out[(size_t)n * 128 + o];
                    out[(size_t)n * 128 + o] = v;
                }
            }
        }
    }
}

// ---------------------------------------------------------------------------
extern "C" void kernel_launch(void* const* d_in, const int* in_sizes, int n_in,
                              void* d_out, int out_size, void* d_ws, size_t ws_size,
                              hipStream_t stream) {
    const float* nfeat  = (const float*)d_in[0];
    const float* etype  = (const float*)d_in[1];
    const int*   src    = (const int*)d_in[2];
    const int*   dst    = (const int*)d_in[3];
    const float* W_edge = (const float*)d_in[4];
    const float* W_ne   = (const float*)d_in[5];
    const float* b_ne   = (const float*)d_in[6];
    const float* W_self = (const float*)d_in[7];
    const float* b_self = (const float*)d_in[8];
    const float* eps    = (const float*)d_in[9];
    float* out = (float*)d_out;

    char* ws = (char*)d_ws;
    size_t off = 0;
    auto alloc = [&](size_t bytes) { void* p = ws + off; off = (off + bytes + 255) & ~(size_t)255; return p; };
    int*   cnt    = (int*)alloc((size_t)NNODES * 4);
    int*   cur    = (int*)alloc((size_t)NNODES * 4);
    int*   part   = (int*)alloc((size_t)EG * 4);
    int*   perm   = (int*)alloc((size_t)NEDGES * 4);
    short* WcatB  = (short*)alloc((size_t)OUT_DIM * KDIM * 2);
    short* WselfB = (short*)alloc((size_t)OUT_DIM * IN_DIM * 2);

    void* args[] = {
        (void*)&nfeat, (void*)&etype, (void*)&src, (void*)&dst,
        (void*)&W_edge, (void*)&W_ne, (void*)&b_ne, (void*)&W_self,
        (void*)&b_self, (void*)&eps,
        (void*)&cnt, (void*)&cur, (void*)&part, (void*)&perm,
        (void*)&WcatB, (void*)&WselfB, (void*)&out
    };
    hipError_t err = hipLaunchCooperativeKernel((const void*)mega, dim3(EG),
                                                dim3(256), args, 0, stream);
    if (err != hipSuccess) {
        // Fallback: R3 multi-kernel pipeline (correct, ~505 us)
        hipMemsetAsync(cnt, 0, (size_t)NNODES * 4, stream);
        hipMemsetAsync(out, 0, (size_t)NNODES * 128 * sizeof(float), stream);
        prep_weights<<<144, 256, 0, stream>>>(W_edge, W_ne, W_self, WcatB, WselfB);
        hist_kernel<<<(NEDGES + 255) / 256, 256, 0, stream>>>(dst, cnt);
        scan_kernel<<<1, 1024, 0, stream>>>(cnt, cur);
        scatter_kernel<<<(NEDGES + 255) / 256, 256, 0, stream>>>(dst, cur, perm);
        edge_kernel<<<EG, 256, 0, stream>>>(nfeat, etype, perm, src, dst, b_ne,
                                            WcatB, out);
        node_kernel<<<(NNODES + 63) / 64, 256, 0, stream>>>(nfeat, b_self, eps,
                                                            WselfB, out);
    }
}

// Round 5
// 498.255 us; speedup vs baseline: 2.0369x; 2.0369x over previous
//
#include <hip/hip_runtime.h>
#include <hip/hip_bf16.h>

#define NNODES 50000
#define NEDGES 800000
#define IN_DIM 128
#define EDGE_DIM 32
#define OUT_DIM 128
#define KDIM 160          // IN_DIM + EDGE_DIM
#define A_STRIDE 168      // 160 + 8 pad, 16B aligned rows
#define NS 136            // 128 + 8 pad for node kernel
#define MS2 130           // bf16 m-tile stride
#define NT (NEDGES / 64)  // 12500 edge tiles
#define EG 512            // edge grid: 2 blocks/CU (LDS-limited)
#define TPB ((NT + EG - 1) / EG)   // 25 tiles per block

typedef __attribute__((ext_vector_type(8))) short short8;
typedef __attribute__((ext_vector_type(4))) short short4v;
typedef __attribute__((ext_vector_type(4))) float floatx4;

__device__ __forceinline__ short f2bf(float f) {
    union { float f; unsigned u; } v; v.f = f;
    unsigned r = (v.u + 0x7FFFu + ((v.u >> 16) & 1u)) >> 16;  // RNE
    return (short)r;
}

__device__ __forceinline__ void store_bf4(short* p, floatx4 v) {
    short4v s;
    s.x = f2bf(v.x); s.y = f2bf(v.y); s.z = f2bf(v.z); s.w = f2bf(v.w);
    *(short4v*)p = s;
}

__device__ __forceinline__ void store_bf8(short* p, floatx4 a, floatx4 b) {
    short8 s;
    s[0] = f2bf(a.x); s[1] = f2bf(a.y); s[2] = f2bf(a.z); s[3] = f2bf(a.w);
    s[4] = f2bf(b.x); s[5] = f2bf(b.y); s[6] = f2bf(b.z); s[7] = f2bf(b.w);
    *(short8*)p = s;
}

#define MFMA8(ACC, A0, A1, B0, B1, B2, B3)                                        \
    ACC[0][0] = __builtin_amdgcn_mfma_f32_16x16x32_bf16(A0, B0, ACC[0][0], 0, 0, 0); \
    ACC[0][1] = __builtin_amdgcn_mfma_f32_16x16x32_bf16(A0, B1, ACC[0][1], 0, 0, 0); \
    ACC[0][2] = __builtin_amdgcn_mfma_f32_16x16x32_bf16(A0, B2, ACC[0][2], 0, 0, 0); \
    ACC[0][3] = __builtin_amdgcn_mfma_f32_16x16x32_bf16(A0, B3, ACC[0][3], 0, 0, 0); \
    ACC[1][0] = __builtin_amdgcn_mfma_f32_16x16x32_bf16(A1, B0, ACC[1][0], 0, 0, 0); \
    ACC[1][1] = __builtin_amdgcn_mfma_f32_16x16x32_bf16(A1, B1, ACC[1][1], 0, 0, 0); \
    ACC[1][2] = __builtin_amdgcn_mfma_f32_16x16x32_bf16(A1, B2, ACC[1][2], 0, 0, 0); \
    ACC[1][3] = __builtin_amdgcn_mfma_f32_16x16x32_bf16(A1, B3, ACC[1][3], 0, 0, 0);

// ---------------------------------------------------------------------------
// Prep: zero out + cnt, convert nfeat -> bf16 table, build folded weights.
// ---------------------------------------------------------------------------
__global__ __launch_bounds__(256) void prep_kernel(
    const float* __restrict__ nfeat, const float* __restrict__ W_edge,
    const float* __restrict__ W_ne, const float* __restrict__ W_self,
    float* __restrict__ out, int* __restrict__ cnt, short* __restrict__ nfB,
    short* __restrict__ WcatB, short* __restrict__ WselfB)
{
    int gid = blockIdx.x * 256 + threadIdx.x;
    int GS = gridDim.x * 256;
    // zero output (doubles as neigh accumulator; handles deg==0)
    for (int i = gid; i < NNODES * OUT_DIM / 4; i += GS)
        ((floatx4*)out)[i] = (floatx4){0.f, 0.f, 0.f, 0.f};
    for (int i = gid; i < NNODES; i += GS) cnt[i] = 0;
    // nfeat -> bf16 (halves gather traffic in edge/node kernels)
    for (int i = gid; i < NNODES * IN_DIM / 8; i += GS) {
        floatx4 a = ((const floatx4*)nfeat)[2 * i];
        floatx4 b = ((const floatx4*)nfeat)[2 * i + 1];
        store_bf8(nfB + 8 * i, a, b);
    }
    // weights: WcatB[n][k] = k<128 ? W_ne[n][k] : (W2 @ W_edge)[n][k-128]
    for (int idx = gid; idx < OUT_DIM * KDIM + OUT_DIM * IN_DIM; idx += GS) {
        if (idx < OUT_DIM * KDIM) {
            int n = idx / KDIM, k = idx - n * KDIM;
            float val;
            if (k < IN_DIM) {
                val = W_ne[n * 256 + k];
            } else {
                int j = k - IN_DIM;
                float s = 0.f;
                for (int kk = 0; kk < 128; ++kk)
                    s += W_ne[n * 256 + 128 + kk] * W_edge[kk * 32 + j];
                val = s;
            }
            WcatB[idx] = f2bf(val);
        } else {
            int s = idx - OUT_DIM * KDIM;
            WselfB[s] = f2bf(W_self[s]);
        }
    }
}

// ---------------------------------------------------------------------------
// Counting sort: histogram -> single-block scan -> scatter.
// Scatter materializes sorted esrc/edst AND bf16 etype rows (etB) so the
// edge kernel reads everything except the nfeat gather contiguously.
// ---------------------------------------------------------------------------
__global__ void hist_kernel(const int* __restrict__ dst, int* __restrict__ cnt) {
    int e = blockIdx.x * 256 + threadIdx.x;
    if (e < NEDGES) atomicAdd(&cnt[dst[e]], 1);
}

__global__ __launch_bounds__(1024) void scan_kernel(const int* __restrict__ cnt,
                                                    int* __restrict__ cur) {
    __shared__ int bufA[1024], bufB[1024];
    const int CH = 49;                       // 49*1024 >= 50000
    int t = threadIdx.x;
    int beg = t * CH, end = min(beg + CH, NNODES);
    int s = 0;
    for (int i = beg; i < end; ++i) s += cnt[i];
    bufA[t] = s;
    __syncthreads();
    int* in = bufA; int* out = bufB;
    for (int off = 1; off < 1024; off <<= 1) {
        out[t] = in[t] + (t >= off ? in[t - off] : 0);
        __syncthreads();
        int* tmp = in; in = out; out = tmp;
    }
    int base = in[t] - s;
    for (int i = beg; i < end; ++i) { cur[i] = base; base += cnt[i]; }
}

__global__ void scatter_kernel(const int* __restrict__ src,
                               const int* __restrict__ dst,
                               const float* __restrict__ etype,
                               int* __restrict__ cur,      // cursor (destroyed)
                               int* __restrict__ esrc, int* __restrict__ edst,
                               short* __restrict__ etB) {
    int e = blockIdx.x * 256 + threadIdx.x;
    if (e < NEDGES) {
        int d = dst[e];
        int pos = atomicAdd(&cur[d], 1);
        esrc[pos] = src[e];
        edst[pos] = d;
        const floatx4* row = (const floatx4*)(etype + (size_t)e * 32);
        short* o = etB + (size_t)pos * 32;
        #pragma unroll
        for (int j = 0; j < 4; ++j)
            store_bf8(o + 8 * j, row[2 * j], row[2 * j + 1]);
    }
}

// ---------------------------------------------------------------------------
// Edge kernel: persistent, 512 blocks x 25 tiles of 64 dst-sorted edges.
// All inputs bf16; only the nfB row gather is non-contiguous.
// ---------------------------------------------------------------------------
__global__ __launch_bounds__(256) void edge_kernel(
    const short* __restrict__ nfB, const short* __restrict__ etB,
    const int* __restrict__ esrc, const int* __restrict__ edst,
    const float* __restrict__ b_ne, const short* __restrict__ WcatB,
    float* __restrict__ out)
{
    __shared__ short As[64 * A_STRIDE];          // 21504 B
    __shared__ short Bs[128 * A_STRIDE];         // 43008 B
    __shared__ unsigned short mbufh[64 * MS2];   // 16640 B
    __shared__ int dsts[2][64];
    const int tid = threadIdx.x;

    // stage B once per block (L2-hot)
    {
        int r = tid >> 1, h = tid & 1;
        const short8* g = (const short8*)(WcatB + r * KDIM + h * 80);
        short* l = Bs + r * A_STRIDE + h * 80;
        #pragma unroll
        for (int c = 0; c < 10; ++c)
            *(short8*)(l + 8 * c) = g[c];
    }

    const int lane = tid & 63;
    const int w = tid >> 6;
    const int et = w & 1;                        // edge half
    const int nh = w >> 1;                       // out-col half
    const int li = lane & 15, q = lane >> 4;
    const short* Ab = As + (et * 32 + li) * A_STRIDE + q * 8;
    const short* Bb = Bs + (nh * 64 + li) * A_STRIDE + q * 8;

    float bias[4];
    #pragma unroll
    for (int tb = 0; tb < 4; ++tb) bias[tb] = b_ne[nh * 64 + tb * 16 + li];

    const int t0 = blockIdx.x * TPB;
    const int t1 = min(t0 + TPB, NT);
    const int ee = tid >> 2, ec = tid & 3;       // 4 threads per edge

    for (int t = t0; t < t1; ++t) {
        const int e0 = t * 64;
        const int par = t & 1;

        if (tid < 64) dsts[par][tid] = edst[e0 + tid];
        {
            // nfeat bf16 row: 128 shorts = 16 short8; 4 per thread
            int s = esrc[e0 + ee];
            const short8* nr = (const short8*)(nfB + (size_t)s * 128);
            short8 v0 = nr[4 * ec];
            short8 v1 = nr[4 * ec + 1];
            short8 v2 = nr[4 * ec + 2];
            short8 v3 = nr[4 * ec + 3];
            short8 ev = *(const short8*)(etB + (size_t)(e0 + ee) * 32 + 8 * ec);
            short* ap = As + ee * A_STRIDE + 32 * ec;
            *(short8*)(ap)      = v0;
            *(short8*)(ap + 8)  = v1;
            *(short8*)(ap + 16) = v2;
            *(short8*)(ap + 24) = v3;
            *(short8*)(As + ee * A_STRIDE + IN_DIM + 8 * ec) = ev;
        }
        __syncthreads();                         // A ready; prev scan done

        floatx4 acc[2][4];
        #pragma unroll
        for (int i = 0; i < 2; ++i)
            #pragma unroll
            for (int j = 0; j < 4; ++j)
                acc[i][j] = (floatx4){0.f, 0.f, 0.f, 0.f};

        #pragma unroll
        for (int kk = 0; kk < 5; ++kk) {
            short8 a0 = *(const short8*)(Ab + kk * 32);
            short8 a1 = *(const short8*)(Ab + 16 * A_STRIDE + kk * 32);
            short8 b0 = *(const short8*)(Bb + kk * 32);
            short8 b1 = *(const short8*)(Bb + 16 * A_STRIDE + kk * 32);
            short8 b2 = *(const short8*)(Bb + 32 * A_STRIDE + kk * 32);
            short8 b3 = *(const short8*)(Bb + 48 * A_STRIDE + kk * 32);
            MFMA8(acc, a0, a1, b0, b1, b2, b3)
        }

        // m tile (relu + bias) -> LDS bf16; C/D: row = q*4+reg, col = li
        #pragma unroll
        for (int ta = 0; ta < 2; ++ta) {
            #pragma unroll
            for (int r = 0; r < 4; ++r) {
                int el = et * 32 + ta * 16 + q * 4 + r;
                #pragma unroll
                for (int tb = 0; tb < 4; ++tb) {
                    int o = nh * 64 + tb * 16 + li;
                    float v = acc[ta][tb][r] + bias[tb];
                    v = v > 0.f ? v : 0.f;
                    mbufh[el * MS2 + o] = (unsigned short)f2bf(v);
                }
            }
        }
        __syncthreads();                         // mbuf ready

        // per-column run-max over dst-sorted rows; one atomic per run
        {
            int c = tid & 127, h = tid >> 7;
            int r0 = h * 32;
            int curd = dsts[par][r0];
            unsigned best = mbufh[r0 * MS2 + c];
            #pragma unroll 4
            for (int r = 1; r < 32; ++r) {
                int d = dsts[par][r0 + r];
                unsigned bits = mbufh[(r0 + r) * MS2 + c];
                if (d != curd) {
                    atomicMax((int*)out + (size_t)curd * 128 + c,
                              (int)(best << 16));
                    curd = d; best = bits;
                } else {
                    best = best > bits ? best : bits;
                }
            }
            atomicMax((int*)out + (size_t)curd * 128 + c, (int)(best << 16));
        }
    }
}

// ---------------------------------------------------------------------------
// Node kernel (in-place): out = (1+eps)*out + nfeat @ W_self^T + b_self
// ---------------------------------------------------------------------------
__global__ __launch_bounds__(256) void node_kernel(
    const short* __restrict__ nfB, const float* __restrict__ b_self,
    const float* __restrict__ eps, const short* __restrict__ WselfB,
    float* __restrict__ out)
{
    __shared__ short As[64 * NS];
    __shared__ short Bs[128 * NS];
    const int tid = threadIdx.x;
    const int n0 = blockIdx.x * 64;

    {
        int r = tid >> 1, h = tid & 1;
        const short8* g = (const short8*)(WselfB + r * 128 + h * 64);
        short* l = Bs + r * NS + h * 64;
        #pragma unroll
        for (int c = 0; c < 8; ++c)
            *(short8*)(l + 8 * c) = g[c];
    }
    {
        int r = tid >> 2, c = tid & 3;           // 4 threads per row
        int n = n0 + r;
        short* ap = As + r * NS + 32 * c;
        if (n < NNODES) {
            const short8* nr = (const short8*)(nfB + (size_t)n * 128);
            #pragma unroll
            for (int j = 0; j < 4; ++j)
                *(short8*)(ap + 8 * j) = nr[4 * c + j];
        } else {
            #pragma unroll
            for (int j = 0; j < 4; ++j)
                *(short8*)(ap + 8 * j) = (short8){0,0,0,0,0,0,0,0};
        }
    }
    __syncthreads();

    const int lane = tid & 63;
    const int w = tid >> 6;
    const int et = w & 1;
    const int nh = w >> 1;
    const int li = lane & 15, q = lane >> 4;

    floatx4 acc[2][4];
    #pragma unroll
    for (int i = 0; i < 2; ++i)
        #pragma unroll
        for (int j = 0; j < 4; ++j)
            acc[i][j] = (floatx4){0.f, 0.f, 0.f, 0.f};

    const short* Ab = As + (et * 32 + li) * NS + q * 8;
    const short* Bb = Bs + (nh * 64 + li) * NS + q * 8;
    #pragma unroll
    for (int kk = 0; kk < 4; ++kk) {
        short8 a0 = *(const short8*)(Ab + kk * 32);
        short8 a1 = *(const short8*)(Ab + 16 * NS + kk * 32);
        short8 b0 = *(const short8*)(Bb + kk * 32);
        short8 b1 = *(const short8*)(Bb + 16 * NS + kk * 32);
        short8 b2 = *(const short8*)(Bb + 32 * NS + kk * 32);
        short8 b3 = *(const short8*)(Bb + 48 * NS + kk * 32);
        MFMA8(acc, a0, a1, b0, b1, b2, b3)
    }

    const float epsv = 1.0f + eps[0];
    #pragma unroll
    for (int ta = 0; ta < 2; ++ta) {
        #pragma unroll
        for (int r = 0; r < 4; ++r) {
            int n = n0 + et * 32 + ta * 16 + q * 4 + r;
            if (n < NNODES) {
                #pragma unroll
                for (int tb = 0; tb < 4; ++tb) {
                    int o = nh * 64 + tb * 16 + li;
                    float v = acc[ta][tb][r] + b_self[o]
                            + epsv * out[(size_t)n * 128 + o];
                    out[(size_t)n * 128 + o] = v;
                }
            }
        }
    }
}

// ===========================================================================
// Fallback kernels (R1-style direct path) — used only if ws_size too small.
// ===========================================================================
__global__ void prep_w(const float* __restrict__ W_edge,
                       const float* __restrict__ W_ne,
                       const float* __restrict__ W_self,
                       short* __restrict__ WcatB, short* __restrict__ WselfB)
{
    int idx = blockIdx.x * 256 + threadIdx.x;
    if (idx < OUT_DIM * KDIM) {
        int n = idx / KDIM, k = idx - n * KDIM;
        float val;
        if (k < IN_DIM) {
            val = W_ne[n * 256 + k];
        } else {
            int j = k - IN_DIM;
            float s = 0.f;
            for (int kk = 0; kk < 128; ++kk)
                s += W_ne[n * 256 + 128 + kk] * W_edge[kk * 32 + j];
            val = s;
        }
        WcatB[idx] = f2bf(val);
    } else if (idx < OUT_DIM * KDIM + OUT_DIM * IN_DIM) {
        int s = idx - OUT_DIM * KDIM;
        WselfB[s] = f2bf(W_self[s]);
    }
}

__global__ __launch_bounds__(256) void edge_direct(
    const float* __restrict__ nfeat, const float* __restrict__ etype,
    const int* __restrict__ src, const int* __restrict__ dst,
    const float* __restrict__ b_ne, const short* __restrict__ WcatB,
    float* __restrict__ out)
{
    __shared__ short As[64 * A_STRIDE];
    __shared__ short Bs[128 * A_STRIDE];
    const int tid = threadIdx.x;
    const int e0 = blockIdx.x * 64;
    {
        int r = tid >> 1, h = tid & 1;
        const short8* g = (const short8*)(WcatB + r * KDIM + h * 80);
        short* l = Bs + r * A_STRIDE + h * 80;
        #pragma unroll
        for (int c = 0; c < 10; ++c) *(short8*)(l + 8 * c) = g[c];
    }
    {
        const floatx4* ge = (const floatx4*)(etype + (size_t)e0 * 32);
        #pragma unroll
        for (int i = 0; i < 2; ++i) {
            int f = tid + i * 256;
            int e = f >> 3, c = f & 7;
            store_bf4(As + e * A_STRIDE + IN_DIM + 4 * c, ge[f]);
        }
    }
    {
        int g = tid & 15, eo = tid >> 4;
        #pragma unroll
        for (int p = 0; p < 4; ++p) {
            int e = eo + p * 16;
            int s = src[e0 + e];
            const floatx4* row = (const floatx4*)(nfeat + (size_t)s * 128);
            floatx4 v0 = row[g];
            floatx4 v1 = row[g + 16];
            store_bf4(As + e * A_STRIDE + 4 * g, v0);
            store_bf4(As + e * A_STRIDE + 64 + 4 * g, v1);
        }
    }
    __syncthreads();
    const int lane = tid & 63;
    const int w = tid >> 6;
    const int et = w & 1, nh = w >> 1;
    const int li = lane & 15, q = lane >> 4;
    floatx4 acc[2][4];
    #pragma unroll
    for (int i = 0; i < 2; ++i)
        #pragma unroll
        for (int j = 0; j < 4; ++j)
            acc[i][j] = (floatx4){0.f, 0.f, 0.f, 0.f};
    const short* Ab = As + (et * 32 + li) * A_STRIDE + q * 8;
    const short* Bb = Bs + (nh * 64 + li) * A_STRIDE + q * 8;
    #pragma unroll
    for (int kk = 0; kk < 5; ++kk) {
        short8 a0 = *(const short8*)(Ab + kk * 32);
        short8 a1 = *(const short8*)(Ab + 16 * A_STRIDE + kk * 32);
        short8 b0 = *(const short8*)(Bb + kk * 32);
        short8 b1 = *(const short8*)(Bb + 16 * A_STRIDE + kk * 32);
        short8 b2 = *(const short8*)(Bb + 32 * A_STRIDE + kk * 32);
        short8 b3 = *(const short8*)(Bb + 48 * A_STRIDE + kk * 32);
        MFMA8(acc, a0, a1, b0, b1, b2, b3)
    }
    #pragma unroll
    for (int ta = 0; ta < 2; ++ta) {
        #pragma unroll
        for (int r = 0; r < 4; ++r) {
            int el = et * 32 + ta * 16 + q * 4 + r;
            int d = dst[e0 + el];
            int* nrow = (int*)out + (size_t)d * 128;
            #pragma unroll
            for (int tb = 0; tb < 4; ++tb) {
                int o = nh * 64 + tb * 16 + li;
                float v = acc[ta][tb][r] + b_ne[o];
                v = v > 0.f ? v : 0.f;
                atomicMax(nrow + o, __float_as_int(v));
            }
        }
    }
}

__global__ __launch_bounds__(256) void node_direct(
    const float* __restrict__ nfeat, const float* __restrict__ b_self,
    const float* __restrict__ eps, const short* __restrict__ WselfB,
    float* __restrict__ out)
{
    __shared__ short As[64 * NS];
    __shared__ short Bs[128 * NS];
    const int tid = threadIdx.x;
    const int n0 = blockIdx.x * 64;
    {
        int r = tid >> 1, h = tid & 1;
        const short8* g = (const short8*)(WselfB + r * 128 + h * 64);
        short* l = Bs + r * NS + h * 64;
        #pragma unroll
        for (int c = 0; c < 8; ++c) *(short8*)(l + 8 * c) = g[c];
    }
    {
        int r = tid >> 2, fi = tid & 3;
        int n = n0 + r;
        if (n < NNODES) {
            const floatx4* row = (const floatx4*)(nfeat + (size_t)n * 128);
            #pragma unroll
            for (int p = 0; p < 8; ++p) {
                int f = fi + 4 * p;
                store_bf4(As + r * NS + 4 * f, row[f]);
            }
        } else {
            #pragma unroll
            for (int p = 0; p < 8; ++p) {
                int f = fi + 4 * p;
                *(short4v*)(As + r * NS + 4 * f) = (short4v){0, 0, 0, 0};
            }
        }
    }
    __syncthreads();
    const int lane = tid & 63;
    const int w = tid >> 6;
    const int et = w & 1, nh = w >> 1;
    const int li = lane & 15, q = lane >> 4;
    floatx4 acc[2][4];
    #pragma unroll
    for (int i = 0; i < 2; ++i)
        #pragma unroll
        for (int j = 0; j < 4; ++j)
            acc[i][j] = (floatx4){0.f, 0.f, 0.f, 0.f};
    const short* Ab = As + (et * 32 + li) * NS + q * 8;
    const short* Bb = Bs + (nh * 64 + li) * NS + q * 8;
    #pragma unroll
    for (int kk = 0; kk < 4; ++kk) {
        short8 a0 = *(const short8*)(Ab + kk * 32);
        short8 a1 = *(const short8*)(Ab + 16 * NS + kk * 32);
        short8 b0 = *(const short8*)(Bb + kk * 32);
        short8 b1 = *(const short8*)(Bb + 16 * NS + kk * 32);
        short8 b2 = *(const short8*)(Bb + 32 * NS + kk * 32);
        short8 b3 = *(const short8*)(Bb + 48 * NS + kk * 32);
        MFMA8(acc, a0, a1, b0, b1, b2, b3)
    }
    const float epsv = 1.0f + eps[0];
    #pragma unroll
    for (int ta = 0; ta < 2; ++ta) {
        #pragma unroll
        for (int r = 0; r < 4; ++r) {
            int n = n0 + et * 32 + ta * 16 + q * 4 + r;
            if (n < NNODES) {
                #pragma unroll
                for (int tb = 0; tb < 4; ++tb) {
                    int o = nh * 64 + tb * 16 + li;
                    float v = acc[ta][tb][r] + b_self[o]
                            + epsv * out[(size_t)n * 128 + o];
                    out[(size_t)n * 128 + o] = v;
                }
            }
        }
    }
}

// ---------------------------------------------------------------------------
extern "C" void kernel_launch(void* const* d_in, const int* in_sizes, int n_in,
                              void* d_out, int out_size, void* d_ws, size_t ws_size,
                              hipStream_t stream) {
    const float* nfeat  = (const float*)d_in[0];
    const float* etype  = (const float*)d_in[1];
    const int*   src    = (const int*)d_in[2];
    const int*   dst    = (const int*)d_in[3];
    const float* W_edge = (const float*)d_in[4];
    const float* W_ne   = (const float*)d_in[5];
    const float* b_ne   = (const float*)d_in[6];
    const float* W_self = (const float*)d_in[7];
    const float* b_self = (const float*)d_in[8];
    const float* eps    = (const float*)d_in[9];
    float* out = (float*)d_out;

    char* ws = (char*)d_ws;
    size_t off = 0;
    auto alloc = [&](size_t bytes) { void* p = ws + off; off = (off + bytes + 255) & ~(size_t)255; return p; };
    int*   cnt    = (int*)alloc((size_t)NNODES * 4);
    int*   cur    = (int*)alloc((size_t)NNODES * 4);
    int*   esrc   = (int*)alloc((size_t)NEDGES * 4);
    int*   edst   = (int*)alloc((size_t)NEDGES * 4);
    short* nfB    = (short*)alloc((size_t)NNODES * IN_DIM * 2);
    short* etB    = (short*)alloc((size_t)NEDGES * EDGE_DIM * 2);
    short* WcatB  = (short*)alloc((size_t)OUT_DIM * KDIM * 2);
    short* WselfB = (short*)alloc((size_t)OUT_DIM * IN_DIM * 2);
    size_t need = off;

    if (ws_size >= need) {
        prep_kernel<<<1024, 256, 0, stream>>>(nfeat, W_edge, W_ne, W_self,
                                              out, cnt, nfB, WcatB, WselfB);
        hist_kernel<<<(NEDGES + 255) / 256, 256, 0, stream>>>(dst, cnt);
        scan_kernel<<<1, 1024, 0, stream>>>(cnt, cur);
        scatter_kernel<<<(NEDGES + 255) / 256, 256, 0, stream>>>(
            src, dst, etype, cur, esrc, edst, etB);
        edge_kernel<<<EG, 256, 0, stream>>>(nfB, etB, esrc, edst, b_ne,
                                            WcatB, out);
        node_kernel<<<(NNODES + 63) / 64, 256, 0, stream>>>(nfB, b_self, eps,
                                                            WselfB, out);
    } else {
        // R1-style direct path: needs only the two weight buffers
        short* WcatB2  = (short*)d_ws;
        short* WselfB2 = WcatB2 + (size_t)OUT_DIM * KDIM;
        hipMemsetAsync(out, 0, (size_t)NNODES * 128 * sizeof(float), stream);
        prep_w<<<144, 256, 0, stream>>>(W_edge, W_ne, W_self, WcatB2, WselfB2);
        edge_direct<<<NEDGES / 64, 256, 0, stream>>>(nfeat, etype, src, dst,
                                                     b_ne, WcatB2, out);
        node_direct<<<(NNODES + 63) / 64, 256, 0, stream>>>(nfeat, b_self, eps,
                                                            WselfB2, out);
    }
}

// Round 6
// 444.290 us; speedup vs baseline: 2.2844x; 1.1215x over previous
//
#include <hip/hip_runtime.h>
#include <hip/hip_bf16.h>

#define NNODES 50000
#define NEDGES 800000
#define IN_DIM 128
#define EDGE_DIM 32
#define OUT_DIM 128
#define KDIM 160          // IN_DIM + EDGE_DIM
#define A_STRIDE 168      // 160 + 8 pad, 16B aligned rows
#define NS 136            // 128 + 8 pad for node kernel
#define MT_STRIDE 72      // col-major m-tile: 72 shorts = 144 B (16B-aligned rows)
#define NT (NEDGES / 64)  // 12500 edge tiles
#define EG 768            // edge grid: 3 blocks/CU
#define TPB ((NT + EG - 1) / EG)   // 17 tiles per block

typedef __attribute__((ext_vector_type(8))) short short8;
typedef __attribute__((ext_vector_type(4))) short short4v;
typedef __attribute__((ext_vector_type(4))) float floatx4;

__device__ __forceinline__ short f2bf(float f) {
    union { float f; unsigned u; } v; v.f = f;
    unsigned r = (v.u + 0x7FFFu + ((v.u >> 16) & 1u)) >> 16;  // RNE
    return (short)r;
}

__device__ __forceinline__ void store_bf4(short* p, floatx4 v) {
    short4v s;
    s.x = f2bf(v.x); s.y = f2bf(v.y); s.z = f2bf(v.z); s.w = f2bf(v.w);
    *(short4v*)p = s;
}

__device__ __forceinline__ void store_bf8(short* p, floatx4 a, floatx4 b) {
    short8 s;
    s[0] = f2bf(a.x); s[1] = f2bf(a.y); s[2] = f2bf(a.z); s[3] = f2bf(a.w);
    s[4] = f2bf(b.x); s[5] = f2bf(b.y); s[6] = f2bf(b.z); s[7] = f2bf(b.w);
    *(short8*)p = s;
}

#define MFMA8(ACC, A0, A1, B0, B1, B2, B3)                                        \
    ACC[0][0] = __builtin_amdgcn_mfma_f32_16x16x32_bf16(A0, B0, ACC[0][0], 0, 0, 0); \
    ACC[0][1] = __builtin_amdgcn_mfma_f32_16x16x32_bf16(A0, B1, ACC[0][1], 0, 0, 0); \
    ACC[0][2] = __builtin_amdgcn_mfma_f32_16x16x32_bf16(A0, B2, ACC[0][2], 0, 0, 0); \
    ACC[0][3] = __builtin_amdgcn_mfma_f32_16x16x32_bf16(A0, B3, ACC[0][3], 0, 0, 0); \
    ACC[1][0] = __builtin_amdgcn_mfma_f32_16x16x32_bf16(A1, B0, ACC[1][0], 0, 0, 0); \
    ACC[1][1] = __builtin_amdgcn_mfma_f32_16x16x32_bf16(A1, B1, ACC[1][1], 0, 0, 0); \
    ACC[1][2] = __builtin_amdgcn_mfma_f32_16x16x32_bf16(A1, B2, ACC[1][2], 0, 0, 0); \
    ACC[1][3] = __builtin_amdgcn_mfma_f32_16x16x32_bf16(A1, B3, ACC[1][3], 0, 0, 0);

// ---------------------------------------------------------------------------
// Prep: zero out, nfeat -> bf16 table, folded weights, AND dst histogram
// (cnt pre-zeroed by hipMemsetAsync before this kernel).
// ---------------------------------------------------------------------------
__global__ __launch_bounds__(256) void prep_kernel(
    const float* __restrict__ nfeat, const int* __restrict__ dst,
    const float* __restrict__ W_edge, const float* __restrict__ W_ne,
    const float* __restrict__ W_self, float* __restrict__ out,
    int* __restrict__ cnt, short* __restrict__ nfB,
    short* __restrict__ WcatB, short* __restrict__ WselfB)
{
    int gid = blockIdx.x * 256 + threadIdx.x;
    int GS = gridDim.x * 256;
    for (int i = gid; i < NNODES * OUT_DIM / 4; i += GS)
        ((floatx4*)out)[i] = (floatx4){0.f, 0.f, 0.f, 0.f};
    for (int i = gid; i < NNODES * IN_DIM / 8; i += GS) {
        floatx4 a = ((const floatx4*)nfeat)[2 * i];
        floatx4 b = ((const floatx4*)nfeat)[2 * i + 1];
        store_bf8(nfB + 8 * i, a, b);
    }
    for (int idx = gid; idx < OUT_DIM * KDIM + OUT_DIM * IN_DIM; idx += GS) {
        if (idx < OUT_DIM * KDIM) {
            int n = idx / KDIM, k = idx - n * KDIM;
            float val;
            if (k < IN_DIM) {
                val = W_ne[n * 256 + k];
            } else {
                int j = k - IN_DIM;
                float s = 0.f;
                for (int kk = 0; kk < 128; ++kk)
                    s += W_ne[n * 256 + 128 + kk] * W_edge[kk * 32 + j];
                val = s;
            }
            WcatB[idx] = f2bf(val);
        } else {
            int s = idx - OUT_DIM * KDIM;
            WselfB[s] = f2bf(W_self[s]);
        }
    }
    for (int e = gid; e < NEDGES; e += GS)
        atomicAdd(&cnt[dst[e]], 1);
}

// ---------------------------------------------------------------------------
// Counting sort: scan (single block) then scatter of (eidx, esrc, edst).
// ---------------------------------------------------------------------------
__global__ __launch_bounds__(1024) void scan_kernel(const int* __restrict__ cnt,
                                                    int* __restrict__ cur) {
    __shared__ int bufA[1024], bufB[1024];
    const int CH = 49;                       // 49*1024 >= 50000
    int t = threadIdx.x;
    int beg = t * CH, end = min(beg + CH, NNODES);
    int s = 0;
    for (int i = beg; i < end; ++i) s += cnt[i];
    bufA[t] = s;
    __syncthreads();
    int* in = bufA; int* out = bufB;
    for (int off = 1; off < 1024; off <<= 1) {
        out[t] = in[t] + (t >= off ? in[t - off] : 0);
        __syncthreads();
        int* tmp = in; in = out; out = tmp;
    }
    int base = in[t] - s;
    for (int i = beg; i < end; ++i) { cur[i] = base; base += cnt[i]; }
}

__global__ void scatter_kernel(const int* __restrict__ src,
                               const int* __restrict__ dst,
                               int* __restrict__ cur,      // cursor (destroyed)
                               int* __restrict__ eidx, int* __restrict__ esrc,
                               int* __restrict__ edst) {
    int e = blockIdx.x * 256 + threadIdx.x;
    if (e < NEDGES) {
        int d = dst[e];
        int pos = atomicAdd(&cur[d], 1);
        eidx[pos] = e;
        esrc[pos] = src[e];
        edst[pos] = d;
    }
}

// ---------------------------------------------------------------------------
// Edge kernel: persistent; B-fragments live in REGISTERS (loaded once from
// global WcatB, L2-hot). Each wave owns 32 out-cols x all 64 edge-rows.
// Per tile: stage A (5 b128 LDS writes/thread) -> MFMA (4 A-reads, 8 MFMA
// per k-step) -> relu+bias -> col-major mT (8 b64 writes) -> per-column
// run-max over dst-sorted rows (dsts read from global edst, L1-broadcast;
// m read as 4 b128) -> one atomicMax per run.
// LDS: As 21504 + mT 18432 = 39936 B -> 3-4 blocks/CU.
// ---------------------------------------------------------------------------
__global__ __launch_bounds__(256, 3) void edge_kernel(
    const short* __restrict__ nfB, const float* __restrict__ etype,
    const int* __restrict__ eidx, const int* __restrict__ esrc,
    const int* __restrict__ edst, const float* __restrict__ b_ne,
    const short* __restrict__ WcatB, float* __restrict__ out)
{
    __shared__ short As[64 * A_STRIDE];          // 21504 B
    __shared__ unsigned short mT[128 * MT_STRIDE]; // 18432 B, col-major [o][el]

    const int tid = threadIdx.x;
    const int lane = tid & 63;
    const int w = tid >> 6;                      // wave id: cols w*32..w*32+31
    const int li = lane & 15, q = lane >> 4;

    // --- B-fragments to registers (once per block; L2-hot) ---
    short8 bf[2][5];
    #pragma unroll
    for (int ct = 0; ct < 2; ++ct)
        #pragma unroll
        for (int kk = 0; kk < 5; ++kk)
            bf[ct][kk] = *(const short8*)(WcatB +
                (size_t)(w * 32 + ct * 16 + li) * KDIM + kk * 32 + q * 8);

    float bias[2];
    #pragma unroll
    for (int ct = 0; ct < 2; ++ct) bias[ct] = b_ne[w * 32 + ct * 16 + li];

    const int t0 = blockIdx.x * TPB;
    const int t1 = min(t0 + TPB, NT);
    const int ee = tid >> 2, ec = tid & 3;       // 4 threads per edge row

    for (int t = t0; t < t1; ++t) {
        const int e0 = t * 64;

        // --- stage A: nfB row (bf16) + etype row (fp32 -> bf16) ---
        {
            int s = esrc[e0 + ee];
            const short8* nr = (const short8*)(nfB + (size_t)s * 128);
            short8 v0 = nr[4 * ec];
            short8 v1 = nr[4 * ec + 1];
            short8 v2 = nr[4 * ec + 2];
            short8 v3 = nr[4 * ec + 3];
            int ei = eidx[e0 + ee];
            const floatx4* er = (const floatx4*)(etype + (size_t)ei * 32);
            floatx4 f0 = er[2 * ec];
            floatx4 f1 = er[2 * ec + 1];
            short* ap = As + ee * A_STRIDE + 32 * ec;
            *(short8*)(ap)      = v0;
            *(short8*)(ap + 8)  = v1;
            *(short8*)(ap + 16) = v2;
            *(short8*)(ap + 24) = v3;
            store_bf8(As + ee * A_STRIDE + IN_DIM + 8 * ec, f0, f1);
        }
        __syncthreads();                         // A ready; prev scan done

        floatx4 acc[4][2];                       // [row-tile][col-tile]
        #pragma unroll
        for (int i = 0; i < 4; ++i)
            #pragma unroll
            for (int j = 0; j < 2; ++j)
                acc[i][j] = (floatx4){0.f, 0.f, 0.f, 0.f};

        #pragma unroll
        for (int kk = 0; kk < 5; ++kk) {
            short8 a0 = *(const short8*)(As + (0 * 16 + li) * A_STRIDE + kk * 32 + q * 8);
            short8 a1 = *(const short8*)(As + (1 * 16 + li) * A_STRIDE + kk * 32 + q * 8);
            short8 a2 = *(const short8*)(As + (2 * 16 + li) * A_STRIDE + kk * 32 + q * 8);
            short8 a3 = *(const short8*)(As + (3 * 16 + li) * A_STRIDE + kk * 32 + q * 8);
            acc[0][0] = __builtin_amdgcn_mfma_f32_16x16x32_bf16(a0, bf[0][kk], acc[0][0], 0, 0, 0);
            acc[0][1] = __builtin_amdgcn_mfma_f32_16x16x32_bf16(a0, bf[1][kk], acc[0][1], 0, 0, 0);
            acc[1][0] = __builtin_amdgcn_mfma_f32_16x16x32_bf16(a1, bf[0][kk], acc[1][0], 0, 0, 0);
            acc[1][1] = __builtin_amdgcn_mfma_f32_16x16x32_bf16(a1, bf[1][kk], acc[1][1], 0, 0, 0);
            acc[2][0] = __builtin_amdgcn_mfma_f32_16x16x32_bf16(a2, bf[0][kk], acc[2][0], 0, 0, 0);
            acc[2][1] = __builtin_amdgcn_mfma_f32_16x16x32_bf16(a2, bf[1][kk], acc[2][1], 0, 0, 0);
            acc[3][0] = __builtin_amdgcn_mfma_f32_16x16x32_bf16(a3, bf[0][kk], acc[3][0], 0, 0, 0);
            acc[3][1] = __builtin_amdgcn_mfma_f32_16x16x32_bf16(a3, bf[1][kk], acc[3][1], 0, 0, 0);
        }

        // --- relu+bias -> col-major mT; C/D: row = q*4+r, col = li ---
        #pragma unroll
        for (int rt = 0; rt < 4; ++rt) {
            #pragma unroll
            for (int ct = 0; ct < 2; ++ct) {
                floatx4 a = acc[rt][ct];
                short4v s;
                float v0 = a.x + bias[ct]; s.x = f2bf(v0 > 0.f ? v0 : 0.f);
                float v1 = a.y + bias[ct]; s.y = f2bf(v1 > 0.f ? v1 : 0.f);
                float v2 = a.z + bias[ct]; s.z = f2bf(v2 > 0.f ? v2 : 0.f);
                float v3 = a.w + bias[ct]; s.w = f2bf(v3 > 0.f ? v3 : 0.f);
                *(short4v*)((short*)mT + (w * 32 + ct * 16 + li) * MT_STRIDE
                            + rt * 16 + q * 4) = s;
            }
        }
        __syncthreads();                         // mT ready

        // --- per-column run-max; dsts from global (L1-broadcast) ---
        {
            int c = tid & 127, h = tid >> 7;
            int r0 = h * 32;
            const int4* dp = (const int4*)(edst + e0 + r0);
            int dd[32];
            #pragma unroll
            for (int i = 0; i < 8; ++i) {
                int4 v = dp[i];
                dd[4 * i]     = v.x;
                dd[4 * i + 1] = v.y;
                dd[4 * i + 2] = v.z;
                dd[4 * i + 3] = v.w;
            }
            unsigned mval[32];
            #pragma unroll
            for (int j = 0; j < 4; ++j) {
                short8 v = *(const short8*)((const short*)mT + c * MT_STRIDE
                                            + r0 + 8 * j);
                #pragma unroll
                for (int k = 0; k < 8; ++k)
                    mval[8 * j + k] = (unsigned short)v[k];
            }
            int curd = dd[0];
            unsigned best = mval[0];
            #pragma unroll
            for (int r = 1; r < 32; ++r) {
                if (dd[r] != curd) {
                    atomicMax((int*)out + (size_t)curd * 128 + c,
                              (int)(best << 16));
                    curd = dd[r]; best = mval[r];
                } else {
                    best = best > mval[r] ? best : mval[r];
                }
            }
            atomicMax((int*)out + (size_t)curd * 128 + c, (int)(best << 16));
        }
    }
}

// ---------------------------------------------------------------------------
// Node kernel (in-place): out = (1+eps)*out + nfeat @ W_self^T + b_self
// ---------------------------------------------------------------------------
__global__ __launch_bounds__(256) void node_kernel(
    const short* __restrict__ nfB, const float* __restrict__ b_self,
    const float* __restrict__ eps, const short* __restrict__ WselfB,
    float* __restrict__ out)
{
    __shared__ short As[64 * NS];
    __shared__ short Bs[128 * NS];
    const int tid = threadIdx.x;
    const int n0 = blockIdx.x * 64;

    {
        int r = tid >> 1, h = tid & 1;
        const short8* g = (const short8*)(WselfB + r * 128 + h * 64);
        short* l = Bs + r * NS + h * 64;
        #pragma unroll
        for (int c = 0; c < 8; ++c)
            *(short8*)(l + 8 * c) = g[c];
    }
    {
        int r = tid >> 2, c = tid & 3;
        int n = n0 + r;
        short* ap = As + r * NS + 32 * c;
        if (n < NNODES) {
            const short8* nr = (const short8*)(nfB + (size_t)n * 128);
            #pragma unroll
            for (int j = 0; j < 4; ++j)
                *(short8*)(ap + 8 * j) = nr[4 * c + j];
        } else {
            #pragma unroll
            for (int j = 0; j < 4; ++j)
                *(short8*)(ap + 8 * j) = (short8){0,0,0,0,0,0,0,0};
        }
    }
    __syncthreads();

    const int lane = tid & 63;
    const int w = tid >> 6;
    const int et = w & 1;
    const int nh = w >> 1;
    const int li = lane & 15, q = lane >> 4;

    floatx4 acc[2][4];
    #pragma unroll
    for (int i = 0; i < 2; ++i)
        #pragma unroll
        for (int j = 0; j < 4; ++j)
            acc[i][j] = (floatx4){0.f, 0.f, 0.f, 0.f};

    const short* Ab = As + (et * 32 + li) * NS + q * 8;
    const short* Bb = Bs + (nh * 64 + li) * NS + q * 8;
    #pragma unroll
    for (int kk = 0; kk < 4; ++kk) {
        short8 a0 = *(const short8*)(Ab + kk * 32);
        short8 a1 = *(const short8*)(Ab + 16 * NS + kk * 32);
        short8 b0 = *(const short8*)(Bb + kk * 32);
        short8 b1 = *(const short8*)(Bb + 16 * NS + kk * 32);
        short8 b2 = *(const short8*)(Bb + 32 * NS + kk * 32);
        short8 b3 = *(const short8*)(Bb + 48 * NS + kk * 32);
        MFMA8(acc, a0, a1, b0, b1, b2, b3)
    }

    const float epsv = 1.0f + eps[0];
    #pragma unroll
    for (int ta = 0; ta < 2; ++ta) {
        #pragma unroll
        for (int r = 0; r < 4; ++r) {
            int n = n0 + et * 32 + ta * 16 + q * 4 + r;
            if (n < NNODES) {
                #pragma unroll
                for (int tb = 0; tb < 4; ++tb) {
                    int o = nh * 64 + tb * 16 + li;
                    float v = acc[ta][tb][r] + b_self[o]
                            + epsv * out[(size_t)n * 128 + o];
                    out[(size_t)n * 128 + o] = v;
                }
            }
        }
    }
}

// ===========================================================================
// Fallback kernels (R1-style direct path) — used only if ws_size too small.
// ===========================================================================
__global__ void prep_w(const float* __restrict__ W_edge,
                       const float* __restrict__ W_ne,
                       const float* __restrict__ W_self,
                       short* __restrict__ WcatB, short* __restrict__ WselfB)
{
    int idx = blockIdx.x * 256 + threadIdx.x;
    if (idx < OUT_DIM * KDIM) {
        int n = idx / KDIM, k = idx - n * KDIM;
        float val;
        if (k < IN_DIM) {
            val = W_ne[n * 256 + k];
        } else {
            int j = k - IN_DIM;
            float s = 0.f;
            for (int kk = 0; kk < 128; ++kk)
                s += W_ne[n * 256 + 128 + kk] * W_edge[kk * 32 + j];
            val = s;
        }
        WcatB[idx] = f2bf(val);
    } else if (idx < OUT_DIM * KDIM + OUT_DIM * IN_DIM) {
        int s = idx - OUT_DIM * KDIM;
        WselfB[s] = f2bf(W_self[s]);
    }
}

__global__ __launch_bounds__(256) void edge_direct(
    const float* __restrict__ nfeat, const float* __restrict__ etype,
    const int* __restrict__ src, const int* __restrict__ dst,
    const float* __restrict__ b_ne, const short* __restrict__ WcatB,
    float* __restrict__ out)
{
    __shared__ short As[64 * A_STRIDE];
    __shared__ short Bs[128 * A_STRIDE];
    const int tid = threadIdx.x;
    const int e0 = blockIdx.x * 64;
    {
        int r = tid >> 1, h = tid & 1;
        const short8* g = (const short8*)(WcatB + r * KDIM + h * 80);
        short* l = Bs + r * A_STRIDE + h * 80;
        #pragma unroll
        for (int c = 0; c < 10; ++c) *(short8*)(l + 8 * c) = g[c];
    }
    {
        const floatx4* ge = (const floatx4*)(etype + (size_t)e0 * 32);
        #pragma unroll
        for (int i = 0; i < 2; ++i) {
            int f = tid + i * 256;
            int e = f >> 3, c = f & 7;
            store_bf4(As + e * A_STRIDE + IN_DIM + 4 * c, ge[f]);
        }
    }
    {
        int g = tid & 15, eo = tid >> 4;
        #pragma unroll
        for (int p = 0; p < 4; ++p) {
            int e = eo + p * 16;
            int s = src[e0 + e];
            const floatx4* row = (const floatx4*)(nfeat + (size_t)s * 128);
            floatx4 v0 = row[g];
            floatx4 v1 = row[g + 16];
            store_bf4(As + e * A_STRIDE + 4 * g, v0);
            store_bf4(As + e * A_STRIDE + 64 + 4 * g, v1);
        }
    }
    __syncthreads();
    const int lane = tid & 63;
    const int w = tid >> 6;
    const int et = w & 1, nh = w >> 1;
    const int li = lane & 15, q = lane >> 4;
    floatx4 acc[2][4];
    #pragma unroll
    for (int i = 0; i < 2; ++i)
        #pragma unroll
        for (int j = 0; j < 4; ++j)
            acc[i][j] = (floatx4){0.f, 0.f, 0.f, 0.f};
    const short* Ab = As + (et * 32 + li) * A_STRIDE + q * 8;
    const short* Bb = Bs + (nh * 64 + li) * A_STRIDE + q * 8;
    #pragma unroll
    for (int kk = 0; kk < 5; ++kk) {
        short8 a0 = *(const short8*)(Ab + kk * 32);
        short8 a1 = *(const short8*)(Ab + 16 * A_STRIDE + kk * 32);
        short8 b0 = *(const short8*)(Bb + kk * 32);
        short8 b1 = *(const short8*)(Bb + 16 * A_STRIDE + kk * 32);
        short8 b2 = *(const short8*)(Bb + 32 * A_STRIDE + kk * 32);
        short8 b3 = *(const short8*)(Bb + 48 * A_STRIDE + kk * 32);
        MFMA8(acc, a0, a1, b0, b1, b2, b3)
    }
    #pragma unroll
    for (int ta = 0; ta < 2; ++ta) {
        #pragma unroll
        for (int r = 0; r < 4; ++r) {
            int el = et * 32 + ta * 16 + q * 4 + r;
            int d = dst[e0 + el];
            int* nrow = (int*)out + (size_t)d * 128;
            #pragma unroll
            for (int tb = 0; tb < 4; ++tb) {
                int o = nh * 64 + tb * 16 + li;
                float v = acc[ta][tb][r] + b_ne[o];
                v = v > 0.f ? v : 0.f;
                atomicMax(nrow + o, __float_as_int(v));
            }
        }
    }
}

__global__ __launch_bounds__(256) void node_direct(
    const float* __restrict__ nfeat, const float* __restrict__ b_self,
    const float* __restrict__ eps, const short* __restrict__ WselfB,
    float* __restrict__ out)
{
    __shared__ short As[64 * NS];
    __shared__ short Bs[128 * NS];
    const int tid = threadIdx.x;
    const int n0 = blockIdx.x * 64;
    {
        int r = tid >> 1, h = tid & 1;
        const short8* g = (const short8*)(WselfB + r * 128 + h * 64);
        short* l = Bs + r * NS + h * 64;
        #pragma unroll
        for (int c = 0; c < 8; ++c) *(short8*)(l + 8 * c) = g[c];
    }
    {
        int r = tid >> 2, fi = tid & 3;
        int n = n0 + r;
        if (n < NNODES) {
            const floatx4* row = (const floatx4*)(nfeat + (size_t)n * 128);
            #pragma unroll
            for (int p = 0; p < 8; ++p) {
                int f = fi + 4 * p;
                store_bf4(As + r * NS + 4 * f, row[f]);
            }
        } else {
            #pragma unroll
            for (int p = 0; p < 8; ++p) {
                int f = fi + 4 * p;
                *(short4v*)(As + r * NS + 4 * f) = (short4v){0, 0, 0, 0};
            }
        }
    }
    __syncthreads();
    const int lane = tid & 63;
    const int w = tid >> 6;
    const int et = w & 1, nh = w >> 1;
    const int li = lane & 15, q = lane >> 4;
    floatx4 acc[2][4];
    #pragma unroll
    for (int i = 0; i < 2; ++i)
        #pragma unroll
        for (int j = 0; j < 4; ++j)
            acc[i][j] = (floatx4){0.f, 0.f, 0.f, 0.f};
    const short* Ab = As + (et * 32 + li) * NS + q * 8;
    const short* Bb = Bs + (nh * 64 + li) * NS + q * 8;
    #pragma unroll
    for (int kk = 0; kk < 4; ++kk) {
        short8 a0 = *(const short8*)(Ab + kk * 32);
        short8 a1 = *(const short8*)(Ab + 16 * NS + kk * 32);
        short8 b0 = *(const short8*)(Bb + kk * 32);
        short8 b1 = *(const short8*)(Bb + 16 * NS + kk * 32);
        short8 b2 = *(const short8*)(Bb + 32 * NS + kk * 32);
        short8 b3 = *(const short8*)(Bb + 48 * NS + kk * 32);
        MFMA8(acc, a0, a1, b0, b1, b2, b3)
    }
    const float epsv = 1.0f + eps[0];
    #pragma unroll
    for (int ta = 0; ta < 2; ++ta) {
        #pragma unroll
        for (int r = 0; r < 4; ++r) {
            int n = n0 + et * 32 + ta * 16 + q * 4 + r;
            if (n < NNODES) {
                #pragma unroll
                for (int tb = 0; tb < 4; ++tb) {
                    int o = nh * 64 + tb * 16 + li;
                    float v = acc[ta][tb][r] + b_self[o]
                            + epsv * out[(size_t)n * 128 + o];
                    out[(size_t)n * 128 + o] = v;
                }
            }
        }
    }
}

// ---------------------------------------------------------------------------
extern "C" void kernel_launch(void* const* d_in, const int* in_sizes, int n_in,
                              void* d_out, int out_size, void* d_ws, size_t ws_size,
                              hipStream_t stream) {
    const float* nfeat  = (const float*)d_in[0];
    const float* etype  = (const float*)d_in[1];
    const int*   src    = (const int*)d_in[2];
    const int*   dst    = (const int*)d_in[3];
    const float* W_edge = (const float*)d_in[4];
    const float* W_ne   = (const float*)d_in[5];
    const float* b_ne   = (const float*)d_in[6];
    const float* W_self = (const float*)d_in[7];
    const float* b_self = (const float*)d_in[8];
    const float* eps    = (const float*)d_in[9];
    float* out = (float*)d_out;

    char* ws = (char*)d_ws;
    size_t off = 0;
    auto alloc = [&](size_t bytes) { void* p = ws + off; off = (off + bytes + 255) & ~(size_t)255; return p; };
    int*   cnt    = (int*)alloc((size_t)NNODES * 4);
    int*   cur    = (int*)alloc((size_t)NNODES * 4);
    int*   eidx   = (int*)alloc((size_t)NEDGES * 4);
    int*   esrc   = (int*)alloc((size_t)NEDGES * 4);
    int*   edst   = (int*)alloc((size_t)NEDGES * 4);
    short* nfB    = (short*)alloc((size_t)NNODES * IN_DIM * 2);
    short* WcatB  = (short*)alloc((size_t)OUT_DIM * KDIM * 2);
    short* WselfB = (short*)alloc((size_t)OUT_DIM * IN_DIM * 2);
    size_t need = off;

    if (ws_size >= need) {
        hipMemsetAsync(cnt, 0, (size_t)NNODES * 4, stream);
        prep_kernel<<<1024, 256, 0, stream>>>(nfeat, dst, W_edge, W_ne, W_self,
                                              out, cnt, nfB, WcatB, WselfB);
        scan_kernel<<<1, 1024, 0, stream>>>(cnt, cur);
        scatter_kernel<<<(NEDGES + 255) / 256, 256, 0, stream>>>(
            src, dst, cur, eidx, esrc, edst);
        edge_kernel<<<EG, 256, 0, stream>>>(nfB, etype, eidx, esrc, edst,
                                            b_ne, WcatB, out);
        node_kernel<<<(NNODES + 63) / 64, 256, 0, stream>>>(nfB, b_self, eps,
                                                            WselfB, out);
    } else {
        short* WcatB2  = (short*)d_ws;
        short* WselfB2 = WcatB2 + (size_t)OUT_DIM * KDIM;
        hipMemsetAsync(out, 0, (size_t)NNODES * 128 * sizeof(float), stream);
        prep_w<<<144, 256, 0, stream>>>(W_edge, W_ne, W_self, WcatB2, WselfB2);
        edge_direct<<<NEDGES / 64, 256, 0, stream>>>(nfeat, etype, src, dst,
                                                     b_ne, WcatB2, out);
        node_direct<<<(NNODES + 63) / 64, 256, 0, stream>>>(nfeat, b_self, eps,
                                                            WselfB2, out);
    }
}